// Round 12
// baseline (300.271 us; speedup 1.0000x reference)
//
#include <hip/hip_runtime.h>
#include <hip/hip_bf16.h>

#define B_ROWS 131072
#define TWO_PI_F 6.28318530717958647692f

// Output layout (float32 element offsets into d_out):
#define OUT_TOP    393216
#define OUT_SEL    786432
#define OUT_LOGITS 917504
#define OUT_PROBS  9306112

// Workspace layout (int32 element offsets):
#define WS_SEL    0          // sel[131072]
#define WS_BLK    131072     // per-block hist -> scatter bases [512*64]
#define WS_ROWS   163840     // padded rowsArr[147456] (576 groups * 256)
#define WS_GMOD   311296     // groupModel[576]
#define WS_TOT    311872     // per-model totals [64]
#define NGRP3     576        // max groups of 256 rows (512 + 63 pad + slack)

// LDS float offsets for k_mlp4 (dynamic shared):
#define LW1   0
#define LW2   4096
#define LW3   8192
#define LW0   12288   // [64][8] padded rows
#define LB0   12800
#define LB1   12864
#define LB2   12928
#define LB3   12992
#define LW4   13056   // [3][64]
#define LB4   13248   // [3] (+1 pad)
#define LSLAB 13252   // slab[64][256]: pure scratch, bank = tid%32, conflict-free
#define LTOT  (13252 + 64 * 256)          // 29636 floats
#define LDS_BYTES (LTOT * 4)              // 118544 B

typedef float vfloat4 __attribute__((ext_vector_type(4)));

// ---------------- k_prep: selection + per-block hist + totals + constant fills ----------
__global__ __launch_bounds__(256) void k_prep(const float* __restrict__ in,
                                              float* __restrict__ out,
                                              int* __restrict__ sel,
                                              int* __restrict__ blkCnt,
                                              int* __restrict__ tot) {
    __shared__ int hist[64];
    const int tid = threadIdx.x, bid = blockIdx.x;
    if (tid < 64) hist[tid] = 0;
    __syncthreads();

    const int r = bid * 256 + tid;  // grid exactly 512x256
    const float xx = in[r * 6 + 0];
    const float zz = in[r * 6 + 2];
    float a = atan2f(zz, xx);
    a = fmodf(a + TWO_PI_F, TWO_PI_F);
    const float t = a / TWO_PI_F * 64.0f;
    int s = (int)floorf(t);
    s = s < 0 ? 0 : (s > 63 ? 63 : s);
    sel[r] = s;
    out[OUT_SEL + r] = (float)s;
    atomicAdd(&hist[s], 1);

    {
        vfloat4* lg = (vfloat4*)(out + OUT_LOGITS);
        vfloat4* pb = (vfloat4*)(out + OUT_PROBS);
        const vfloat4 ones = {1.f, 1.f, 1.f, 1.f};
        const vfloat4 pr = {0.015625f, 0.015625f, 0.015625f, 0.015625f};
#pragma unroll
        for (int k = 0; k < 16; ++k) {
            __builtin_nontemporal_store(ones, lg + r + k * B_ROWS);
            __builtin_nontemporal_store(pr, pb + r + k * B_ROWS);
        }
    }

    __syncthreads();
    if (tid < 64) {
        blkCnt[bid * 64 + tid] = hist[tid];
        atomicAdd(&tot[tid], hist[tid]);
    }
}

// ---------------- k_scanwrite: 64 blocks; block bm owns model bm -----------------------
__global__ __launch_bounds__(64) void k_scanwrite(int* __restrict__ blkCnt,
                                                  const int* __restrict__ tot,
                                                  int* __restrict__ gmodel,
                                                  int* __restrict__ rowsArr) {
    const int lane = threadIdx.x;
    const int bm = blockIdx.x;

    const int t_l = tot[lane];
    const int grp_l = (t_l + 255) >> 8;
    int inc = grp_l;
#pragma unroll
    for (int off = 1; off < 64; off <<= 1) {
        const int n = __shfl_up(inc, off, 64);
        if (lane >= off) inc += n;
    }
    const int exg = inc - grp_l;
    const int offG = __shfl(exg, bm, 64);
    const int myGrp = __shfl(grp_l, bm, 64);
    const int myT = __shfl(t_l, bm, 64);
    const int totG = __shfl(inc, 63, 64);
    const int padBase = offG << 8;

    for (int i = lane; i < myGrp; i += 64) gmodel[offG + i] = bm;
    if (bm == 63) {
        for (int i = totG + lane; i < NGRP3; i += 64) gmodel[i] = -1;
    }
    for (int i = myT + lane; i < (myGrp << 8); i += 64) rowsArr[padBase + i] = -1;

    // segmented scan over 512 block-counts of model bm
    int c[8];
    int s = 0;
#pragma unroll
    for (int j = 0; j < 8; ++j) c[j] = blkCnt[(lane * 8 + j) * 64 + bm];
#pragma unroll
    for (int j = 0; j < 8; ++j) { const int v = c[j]; c[j] = s; s += v; }
    int incs = s;
#pragma unroll
    for (int off = 1; off < 64; off <<= 1) {
        const int n = __shfl_up(incs, off, 64);
        if (lane >= off) incs += n;
    }
    const int exs = incs - s;
#pragma unroll
    for (int j = 0; j < 8; ++j) blkCnt[(lane * 8 + j) * 64 + bm] = padBase + exs + c[j];
}

// ---------------- k_scatter: per-block reserved ranges, LDS atomics only ----------------
__global__ __launch_bounds__(256) void k_scatter(const int* __restrict__ sel,
                                                 const int* __restrict__ blkBase,
                                                 int* __restrict__ rowsArr) {
    __shared__ int cur[64];
    const int tid = threadIdx.x, bid = blockIdx.x;
    if (tid < 64) cur[tid] = blkBase[bid * 64 + tid];
    __syncthreads();
    const int r = bid * 256 + tid;
    const int s = sel[r];
    const int pos = atomicAdd(&cur[s], 1);
    rowsArr[pos] = r;
}

// one 64->64 layer: h in VGPRs throughout (read-only); slab is write-then-readback
// scratch only (no read-after-write alias window for the allocator to fear).
__device__ __forceinline__ void layer64b(const float* __restrict__ lw,
                                         const float* __restrict__ lb,
                                         float* __restrict__ slab, int tid,
                                         float (&h)[64]) {
#pragma unroll 1
    for (int c = 0; c < 8; ++c) {
        const float* wbase = lw + c * 512;   // 8 output rows of 64
        float acc[8];
#pragma unroll
        for (int j = 0; j < 8; ++j) acc[j] = lb[c * 8 + j];
#pragma unroll
        for (int j = 0; j < 8; ++j) {
            const float4* wr = (const float4*)(wbase + j * 64);
#pragma unroll
            for (int q = 0; q < 16; ++q) {
                const float4 wv = wr[q];
                acc[j] = fmaf(wv.x, h[4 * q + 0], acc[j]);
                acc[j] = fmaf(wv.y, h[4 * q + 1], acc[j]);
                acc[j] = fmaf(wv.z, h[4 * q + 2], acc[j]);
                acc[j] = fmaf(wv.w, h[4 * q + 3], acc[j]);
            }
        }
        float* sd = slab + (c * 8) * 256 + tid;
#pragma unroll
        for (int j = 0; j < 8; ++j) sd[j * 256] = fmaxf(acc[j], 0.f);
    }
    // static readback into registers (per-thread private column; DS ops in-order)
#pragma unroll
    for (int j = 0; j < 64; ++j) h[j] = slab[j * 256 + tid];
}

__global__ __launch_bounds__(256, 1) void k_mlp4(
    const float* __restrict__ in,
    const float* __restrict__ w0, const float* __restrict__ b0,
    const float* __restrict__ w1, const float* __restrict__ b1,
    const float* __restrict__ w2, const float* __restrict__ b2,
    const float* __restrict__ w3, const float* __restrict__ b3,
    const float* __restrict__ w4, const float* __restrict__ b4,
    const int* __restrict__ gmodel, const int* __restrict__ rowsArr,
    float* __restrict__ out) {
    extern __shared__ float lds[];
    const int gidx = blockIdx.x;
    const int m = gmodel[gidx];
    if (m < 0) return;
    const int tid = threadIdx.x;
    float* slab = lds + LSLAB;

    // ---- stage all weights into LDS (coalesced float4 / scalars) ----
    {
        const float4* s1 = (const float4*)(w1 + (size_t)m * 4096);
        const float4* s2 = (const float4*)(w2 + (size_t)m * 4096);
        const float4* s3 = (const float4*)(w3 + (size_t)m * 4096);
        float4* d1 = (float4*)(lds + LW1);
        float4* d2 = (float4*)(lds + LW2);
        float4* d3 = (float4*)(lds + LW3);
#pragma unroll
        for (int k = 0; k < 4; ++k) {
            d1[tid + 256 * k] = s1[tid + 256 * k];
            d2[tid + 256 * k] = s2[tid + 256 * k];
            d3[tid + 256 * k] = s3[tid + 256 * k];
        }
        if (tid < 64) {
            const float* s0 = w0 + m * 384 + tid * 6;
            float* dd = lds + LW0 + tid * 8;
            dd[0] = s0[0]; dd[1] = s0[1]; dd[2] = s0[2];
            dd[3] = s0[3]; dd[4] = s0[4]; dd[5] = s0[5];
            lds[LB0 + tid] = b0[m * 64 + tid];
            lds[LB1 + tid] = b1[m * 64 + tid];
            lds[LB2 + tid] = b2[m * 64 + tid];
            lds[LB3 + tid] = b3[m * 64 + tid];
        }
        if (tid < 192) lds[LW4 + tid] = w4[m * 192 + tid];
        if (tid < 3) lds[LB4 + tid] = b4[m * 3 + tid];
    }
    __syncthreads();

    const int row = rowsArr[gidx * 256 + tid];
    const bool valid = row >= 0;
    const int r = valid ? row : 0;

    const float2 xv0 = *(const float2*)(in + (size_t)r * 6);
    const float2 xv1 = *(const float2*)(in + (size_t)r * 6 + 2);
    const float2 xv2 = *(const float2*)(in + (size_t)r * 6 + 4);
    const float x0 = xv0.x, x1 = xv0.y, x2 = xv1.x, x3 = xv1.y, x4 = xv2.x, x5 = xv2.y;

    float h[64];

    // ---- layer 0: 6 -> 64, fully static into registers (no slab) ----
#pragma unroll
    for (int o = 0; o < 64; ++o) {
        const float4 wa = *(const float4*)(lds + LW0 + o * 8);
        const float2 wb = *(const float2*)(lds + LW0 + o * 8 + 4);
        float a = lds[LB0 + o];
        a = fmaf(wa.x, x0, a);
        a = fmaf(wa.y, x1, a);
        a = fmaf(wa.z, x2, a);
        a = fmaf(wa.w, x3, a);
        a = fmaf(wb.x, x4, a);
        a = fmaf(wb.y, x5, a);
        h[o] = fmaxf(a, 0.f);
    }

    // ---- layers 1..3 ----
#pragma unroll 1
    for (int l = 0; l < 3; ++l) {
        layer64b(lds + l * 4096, lds + LB1 + l * 64, slab, tid, h);
    }

    // ---- layer 4: 64 -> 3 (static, no slab) ----
    float y[3];
#pragma unroll
    for (int c = 0; c < 3; ++c) {
        const float* wr = lds + LW4 + c * 64;
        float a = lds[LB4 + c];
        float cc = 0.f;
#pragma unroll
        for (int q = 0; q < 8; ++q) {
            const float4 wv = ((const float4*)wr)[q];
            const float4 wv2 = ((const float4*)wr)[q + 8];
            a = fmaf(wv.x, h[4 * q + 0], a);
            cc = fmaf(wv2.x, h[32 + 4 * q + 0], cc);
            a = fmaf(wv.y, h[4 * q + 1], a);
            cc = fmaf(wv2.y, h[32 + 4 * q + 1], cc);
            a = fmaf(wv.z, h[4 * q + 2], a);
            cc = fmaf(wv2.z, h[32 + 4 * q + 2], cc);
            a = fmaf(wv.w, h[4 * q + 3], a);
            cc = fmaf(wv2.w, h[32 + 4 * q + 3], cc);
        }
        y[c] = a + cc;
    }
    if (valid) {
        out[row * 3 + 0] = y[0]; out[row * 3 + 1] = y[1]; out[row * 3 + 2] = y[2];
        float* top = out + OUT_TOP;
        top[row * 3 + 0] = y[0]; top[row * 3 + 1] = y[1]; top[row * 3 + 2] = y[2];
    }
}

extern "C" void kernel_launch(void* const* d_in, const int* in_sizes, int n_in,
                              void* d_out, int out_size, void* d_ws, size_t ws_size,
                              hipStream_t stream) {
    const float* in = (const float*)d_in[0];
    const float* w0 = (const float*)d_in[1];
    const float* b0 = (const float*)d_in[2];
    const float* w1 = (const float*)d_in[3];
    const float* b1 = (const float*)d_in[4];
    const float* w2 = (const float*)d_in[5];
    const float* b2 = (const float*)d_in[6];
    const float* w3 = (const float*)d_in[7];
    const float* b3 = (const float*)d_in[8];
    const float* w4 = (const float*)d_in[9];
    const float* b4 = (const float*)d_in[10];
    float* out = (float*)d_out;
    int* ws = (int*)d_ws;

    int* sel = ws + WS_SEL;
    int* blkCnt = ws + WS_BLK;
    int* rowsArr = ws + WS_ROWS;
    int* gmodel = ws + WS_GMOD;
    int* tot = ws + WS_TOT;

    (void)hipFuncSetAttribute(reinterpret_cast<const void*>(k_mlp4),
                              hipFuncAttributeMaxDynamicSharedMemorySize, LDS_BYTES);
    (void)hipMemsetAsync(tot, 0, 64 * sizeof(int), stream);

    k_prep<<<512, 256, 0, stream>>>(in, out, sel, blkCnt, tot);
    k_scanwrite<<<64, 64, 0, stream>>>(blkCnt, tot, gmodel, rowsArr);
    k_scatter<<<512, 256, 0, stream>>>(sel, blkCnt, rowsArr);
    k_mlp4<<<NGRP3, 256, LDS_BYTES, stream>>>(in, w0, b0, w1, b1, w2, b2, w3, b3,
                                              w4, b4, gmodel, rowsArr, out);
}